// Round 5
// baseline (1478.094 us; speedup 1.0000x reference)
//
#include <hip/hip_runtime.h>
#include <stdint.h>

#define NPTS 8000
#define NBATCH 4
#define TOTALP (NBATCH * NPTS)
#define KSEL 32
#define QPB 64    /* queries per block (= lane) */
#define WPB 8     /* waves per block; each wave scans NPTS/WPB candidates */
#define CPW (NPTS / WPB)  /* 1000 */

typedef uint32_t u32;
typedef unsigned long long u64;

// ---------------- Kernel A: encoder + g1/g2 + cand(xyz,n2) precompute -----
// feats = relu(x@ew1+eb1)@ew2+eb2 ; g1 = feats@f1w ; g2 = feats@f2w
// Also emits cand[p] = float4(x,y,z, n2) with np-rounded n2 (serial rn sums).
__global__ __launch_bounds__(256) void encode_kernel(
    const float* __restrict__ x,
    const float* __restrict__ ew1, const float* __restrict__ eb1,
    const float* __restrict__ ew2, const float* __restrict__ eb2,
    const float* __restrict__ f1w, const float* __restrict__ f2w,
    float* __restrict__ g1, float* __restrict__ g2,
    float4* __restrict__ cand)
{
    __shared__ float sw1[9 * 64];
    __shared__ float sw2[64 * 64];
    __shared__ float sf1[64 * 64];
    __shared__ float sf2[64 * 64];
    __shared__ float sb1[64];
    __shared__ float sb2[64];
    __shared__ float shb[4][64];
    __shared__ float sfb[4][64];

    const int tid = threadIdx.x;
    for (int i = tid; i < 9 * 64; i += 256) sw1[i] = ew1[i];
    for (int i = tid; i < 64 * 64; i += 256) {
        sw2[i] = ew2[i]; sf1[i] = f1w[i]; sf2[i] = f2w[i];
    }
    if (tid < 64) { sb1[tid] = eb1[tid]; sb2[tid] = eb2[tid]; }
    __syncthreads();

    const int lane = tid & 63;
    const int w = tid >> 6;
    const int gw = blockIdx.x * 4 + w;
    const int nw = 256 * 4;  // grid fixed at 256 blocks

    #pragma unroll 1
    for (int it = 0; it < 32; ++it) {
        int p = gw + it * nw;
        int pc = p < TOTALP ? p : TOTALP - 1;
        const float* xp = x + (size_t)pc * 9;

        float acc = sb1[lane];
        #pragma unroll
        for (int i = 0; i < 9; ++i) acc = fmaf(xp[i], sw1[i * 64 + lane], acc);
        shb[w][lane] = fmaxf(acc, 0.f);
        __syncthreads();

        float fa = sb2[lane];
        #pragma unroll
        for (int c = 0; c < 64; ++c) fa = fmaf(shb[w][c], sw2[c * 64 + lane], fa);
        sfb[w][lane] = fa;
        __syncthreads();

        float a1 = 0.f, a2 = 0.f;
        #pragma unroll
        for (int c = 0; c < 64; ++c) {
            float fv = sfb[w][c];
            a1 = fmaf(fv, sf1[c * 64 + lane], a1);
            a2 = fmaf(fv, sf2[c * 64 + lane], a2);
        }
        if (p < TOTALP) {
            g1[(size_t)p * 64 + lane] = a1;
            g2[(size_t)p * 64 + lane] = a2;
            if (lane == 0) {
                float cx = xp[0], cy = xp[1], cz = xp[2];
                float n2 = __fadd_rn(__fadd_rn(__fmul_rn(cx, cx),
                                               __fmul_rn(cy, cy)),
                                     __fmul_rn(cz, cz));
                cand[p] = make_float4(cx, cy, cz, n2);
            }
        }
        __syncthreads();
    }
}

// ---------------- Kernel B: np-f32-replicating KNN scan + in-block merge --
// Block = 512 threads = 8 waves; lane = query (64 queries/block); wave w
// scans candidate range [w*1000, w*1000+1000). Metric replicates numpy:
//   dot = fma(z,bz, fma(y,by, rn(x*bx))); d = rn_sub(rn_add(n2q,n2m), rn_mul(2,dot))
// Key = order-mapped f32 bits << 13 | idx (tie = smallest index = lax.top_k).
// Per-range top-32 union-merged (LDS tree) == global top-32 (same total order).
__global__ __launch_bounds__(512) void knn_scan_kernel(
    const float4* __restrict__ cand, int* __restrict__ idxo)
{
    __shared__ u64 mbuf[4][QPB][KSEL + 1];   // +1 pad: break bank aliasing
    const int b = blockIdx.y;
    const int lane = threadIdx.x & 63;
    const int w = threadIdx.x >> 6;
    const int q = blockIdx.x * QPB + lane;   // 125*64 == 8000 exactly
    const float4* cb = cand + (size_t)b * NPTS;

    const float4 qv = cb[q];
    const float qx = qv.x, qy = qv.y, qz = qv.z, qn2 = qv.w;

    u64 sk[KSEL];
    #pragma unroll
    for (int i = 0; i < KSEL; ++i) sk[i] = ~0ULL;
    u64 thr = ~0ULL;
    u64 pd0 = 0, pd1 = 0, pd2 = 0, pd3 = 0;
    int pcnt = 0;

#define DRAIN()                                                         \
    do {                                                                \
        _Pragma("unroll")                                               \
        for (int j = 0; j < 4; ++j) {                                   \
            u64 nk = (j == 0) ? pd0 : (j == 1) ? pd1 : (j == 2) ? pd2 : pd3; \
            if (j >= pcnt) nk = ~0ULL;                                  \
            _Pragma("unroll")                                           \
            for (int t = 0; t < KSEL; ++t) {                            \
                u64 a = sk[t];                                          \
                bool lt = nk < a;                                       \
                sk[t] = lt ? nk : a;                                    \
                nk = lt ? a : nk;                                       \
            }                                                           \
        }                                                               \
        pcnt = 0;                                                       \
        thr = sk[KSEL - 1];                                             \
    } while (0)

#define MAKEKEY(c, ci, keyv)                                            \
    do {                                                                \
        float dot_ = fmaf(qz, (c).z, fmaf(qy, (c).y, __fmul_rn(qx, (c).x))); \
        float d_ = __fsub_rn(__fadd_rn(qn2, (c).w), __fmul_rn(2.0f, dot_)); \
        u32 db_ = __float_as_uint(d_);                                  \
        db_ = (db_ & 0x80000000u) ? ~db_ : (db_ | 0x80000000u);         \
        keyv = (((u64)db_) << 13) | (u64)(ci);                          \
    } while (0)

#define PLACE(keyv)                                                     \
    do {                                                                \
        bool take_ = (keyv) < thr;                                      \
        pd0 = (take_ && pcnt == 0) ? (keyv) : pd0;                      \
        pd1 = (take_ && pcnt == 1) ? (keyv) : pd1;                      \
        pd2 = (take_ && pcnt == 2) ? (keyv) : pd2;                      \
        pd3 = (take_ && pcnt == 3) ? (keyv) : pd3;                      \
        pcnt += (int)take_;                                             \
    } while (0)

    const int c0 = w * CPW;
    #pragma unroll 1
    for (int i = 0; i < CPW; i += 2) {
        float4 ca = cb[c0 + i];
        float4 cc = cb[c0 + i + 1];
        u64 k0, k1;
        MAKEKEY(ca, c0 + i, k0);
        MAKEKEY(cc, c0 + i + 1, k1);
        PLACE(k0);
        PLACE(k1);
        if (__any(pcnt >= 3)) DRAIN();  // pre-group pcnt<=2, +2 -> depth 4 ok
    }
    DRAIN();
#undef PLACE
#undef MAKEKEY
#undef DRAIN

#define INSERT_FROM(kidx)                                               \
    _Pragma("unroll 1")                                                 \
    for (int t = 0; t < KSEL; ++t) {                                    \
        u64 nk = mbuf[kidx][lane][t];                                   \
        _Pragma("unroll")                                               \
        for (int i2 = 0; i2 < KSEL; ++i2) {                             \
            u64 a = sk[i2];                                             \
            bool lt = nk < a;                                           \
            sk[i2] = lt ? nk : a;                                       \
            nk = lt ? a : nk;                                           \
        }                                                               \
    }

    // merge tree: 8 sorted lists -> 1 (waves pairwise, 3 levels)
    if (w & 1) {
        #pragma unroll
        for (int t = 0; t < KSEL; ++t) mbuf[w >> 1][lane][t] = sk[t];
    }
    __syncthreads();
    if (!(w & 1)) { INSERT_FROM(w >> 1); }
    __syncthreads();
    if ((w & 3) == 2) {
        #pragma unroll
        for (int t = 0; t < KSEL; ++t) mbuf[w >> 2][lane][t] = sk[t];
    }
    __syncthreads();
    if ((w & 3) == 0 && (w & 4) == 0) { INSERT_FROM(0); }
    if ((w & 3) == 0 && (w & 4) == 4) { INSERT_FROM(1); }
    __syncthreads();
    if (w == 4) {
        #pragma unroll
        for (int t = 0; t < KSEL; ++t) mbuf[0][lane][t] = sk[t];
    }
    __syncthreads();
    if (w == 0) {
        INSERT_FROM(0);
        int* op = idxo + ((size_t)b * NPTS + q) * KSEL;
        #pragma unroll
        for (int i = 0; i < KSEL; ++i) op[i] = (int)(sk[i] & 0x1FFFULL);
    }
#undef INSERT_FROM
}

// ---------------- Kernel C: gather + edge + relu + maxpool (both fuses) ----
__global__ __launch_bounds__(256) void fuse_kernel(
    const float* __restrict__ g1, const float* __restrict__ g2,
    const int* __restrict__ idxo,
    const float* __restrict__ f1b, const float* __restrict__ f2b,
    float* __restrict__ fused)
{
    const int lane = threadIdx.x & 63;
    const int gw = (int)((blockIdx.x * 256 + threadIdx.x) >> 6);
    const int nw = 512 * 4;  // grid fixed at 512 blocks
    const float bias1 = f1b[lane];
    const float bias2 = f2b[lane];
    for (int p = gw; p < TOTALP; p += nw) {
        int b = p / NPTS;
        const int* mi = idxo + (size_t)p * KSEL;
        const float* G1 = g1 + (size_t)b * NPTS * 64;
        const float* G2 = g2 + (size_t)b * NPTS * 64;
        float base1 = bias1 - g1[(size_t)p * 64 + lane];
        float base2 = bias2 - g2[(size_t)p * 64 + lane];
        float a1 = 0.f, a2 = 0.f;
        #pragma unroll
        for (int k = 0; k < KSEL; ++k) {
            int j = mi[k];
            a1 = fmaxf(a1, G1[(size_t)j * 64 + lane] + base1);
            a2 = fmaxf(a2, G2[(size_t)j * 64 + lane] + base2);
        }
        fused[(size_t)p * 64 + lane] = a1 + a2;
    }
}

// ---------------- Kernel D: classifier MLP ----------------
__global__ __launch_bounds__(256) void cls_kernel(
    const float* __restrict__ fused,
    const float* __restrict__ cw1, const float* __restrict__ cb1,
    const float* __restrict__ cw2, const float* __restrict__ cb2,
    float* __restrict__ out)
{
    __shared__ float sw1[64 * 32];
    __shared__ float sw2[32 * 13];
    __shared__ float sb1[32];
    __shared__ float sb2[13];
    const int tid = threadIdx.x;
    for (int i = tid; i < 64 * 32; i += 256) sw1[i] = cw1[i];
    for (int i = tid; i < 32 * 13; i += 256) sw2[i] = cw2[i];
    if (tid < 32) sb1[tid] = cb1[tid];
    if (tid < 13) sb2[tid] = cb2[tid];
    __syncthreads();

    int p = blockIdx.x * 256 + tid;
    if (p >= TOTALP) return;

    float fu[64];
    const float4* fp = (const float4*)(fused + (size_t)p * 64);
    #pragma unroll
    for (int i = 0; i < 16; ++i) {
        float4 v = fp[i];
        fu[i * 4 + 0] = v.x; fu[i * 4 + 1] = v.y;
        fu[i * 4 + 2] = v.z; fu[i * 4 + 3] = v.w;
    }
    float h[32];
    #pragma unroll
    for (int j = 0; j < 32; j += 4) {
        float ax = sb1[j], ay = sb1[j + 1], az = sb1[j + 2], aw = sb1[j + 3];
        #pragma unroll
        for (int c = 0; c < 64; ++c) {
            float4 wv = *(const float4*)&sw1[c * 32 + j];
            ax = fmaf(fu[c], wv.x, ax);
            ay = fmaf(fu[c], wv.y, ay);
            az = fmaf(fu[c], wv.z, az);
            aw = fmaf(fu[c], wv.w, aw);
        }
        h[j] = fmaxf(ax, 0.f); h[j + 1] = fmaxf(ay, 0.f);
        h[j + 2] = fmaxf(az, 0.f); h[j + 3] = fmaxf(aw, 0.f);
    }
    float* op = out + (size_t)p * 13;
    #pragma unroll
    for (int o = 0; o < 13; ++o) {
        float acc = sb2[o];
        #pragma unroll
        for (int j = 0; j < 32; ++j) acc = fmaf(h[j], sw2[j * 13 + o], acc);
        op[o] = acc;
    }
}

extern "C" void kernel_launch(void* const* d_in, const int* in_sizes, int n_in,
                              void* d_out, int out_size, void* d_ws, size_t ws_size,
                              hipStream_t stream)
{
    const float* x   = (const float*)d_in[0];
    const float* ew1 = (const float*)d_in[1];
    const float* eb1 = (const float*)d_in[2];
    const float* ew2 = (const float*)d_in[3];
    const float* eb2 = (const float*)d_in[4];
    const float* f1w = (const float*)d_in[5];
    const float* f1b = (const float*)d_in[6];
    const float* f2w = (const float*)d_in[7];
    const float* f2b = (const float*)d_in[8];
    const float* cw1 = (const float*)d_in[9];
    const float* cb1 = (const float*)d_in[10];
    const float* cw2 = (const float*)d_in[11];
    const float* cb2 = (const float*)d_in[12];
    float* out = (float*)d_out;

    // workspace (~29.2 MB): [g1 8.2M][g2 8.2M][cand 0.5M][idxo 4.1M][fused 8.2M]
    float*  g1    = (float*)d_ws;
    float*  g2    = g1 + (size_t)TOTALP * 64;
    float4* cand  = (float4*)(g2 + (size_t)TOTALP * 64);
    int*    idxo  = (int*)(cand + (size_t)TOTALP);
    float*  fused = (float*)(idxo + (size_t)TOTALP * KSEL);

    hipLaunchKernelGGL(encode_kernel, dim3(256), dim3(256), 0, stream,
                       x, ew1, eb1, ew2, eb2, f1w, f2w, g1, g2, cand);
    hipLaunchKernelGGL(knn_scan_kernel, dim3(125, NBATCH), dim3(512), 0, stream,
                       cand, idxo);
    hipLaunchKernelGGL(fuse_kernel, dim3(512), dim3(256), 0, stream,
                       g1, g2, idxo, f1b, f2b, fused);
    hipLaunchKernelGGL(cls_kernel, dim3(125), dim3(256), 0, stream,
                       fused, cw1, cb1, cw2, cb2, out);
}

// Round 7
// 718.003 us; speedup vs baseline: 2.0586x; 2.0586x over previous
//
#include <hip/hip_runtime.h>
#include <stdint.h>

#define NPTS 8000
#define NBATCH 4
#define TOTALP (NBATCH * NPTS)
#define KSEL 32
#define QPB 64     /* queries per block (= lane) */
#define SPLIT 8    /* waves per block; wave w scans candidate range w */
#define CPW (NPTS / SPLIT)   /* 1000 */
#define PDEPTH 16  /* pending batch depth per lane */

typedef uint32_t u32;
typedef unsigned long long u64;

// ---------------- Kernel A: encoder + g1/g2 + cand(xyz,n2) precompute -----
__global__ __launch_bounds__(256) void encode_kernel(
    const float* __restrict__ x,
    const float* __restrict__ ew1, const float* __restrict__ eb1,
    const float* __restrict__ ew2, const float* __restrict__ eb2,
    const float* __restrict__ f1w, const float* __restrict__ f2w,
    float* __restrict__ g1, float* __restrict__ g2,
    float4* __restrict__ cand)
{
    __shared__ float sw1[9 * 64];
    __shared__ float sw2[64 * 64];
    __shared__ float sf1[64 * 64];
    __shared__ float sf2[64 * 64];
    __shared__ float sb1[64];
    __shared__ float sb2[64];
    __shared__ float shb[4][64];
    __shared__ float sfb[4][64];

    const int tid = threadIdx.x;
    for (int i = tid; i < 9 * 64; i += 256) sw1[i] = ew1[i];
    for (int i = tid; i < 64 * 64; i += 256) {
        sw2[i] = ew2[i]; sf1[i] = f1w[i]; sf2[i] = f2w[i];
    }
    if (tid < 64) { sb1[tid] = eb1[tid]; sb2[tid] = eb2[tid]; }
    __syncthreads();

    const int lane = tid & 63;
    const int w = tid >> 6;
    const int gw = blockIdx.x * 4 + w;
    const int nw = 256 * 4;  // grid fixed at 256 blocks

    #pragma unroll 1
    for (int it = 0; it < 32; ++it) {
        int p = gw + it * nw;
        int pc = p < TOTALP ? p : TOTALP - 1;
        const float* xp = x + (size_t)pc * 9;

        float acc = sb1[lane];
        #pragma unroll
        for (int i = 0; i < 9; ++i) acc = fmaf(xp[i], sw1[i * 64 + lane], acc);
        shb[w][lane] = fmaxf(acc, 0.f);
        __syncthreads();

        float fa = sb2[lane];
        #pragma unroll
        for (int c = 0; c < 64; ++c) fa = fmaf(shb[w][c], sw2[c * 64 + lane], fa);
        sfb[w][lane] = fa;
        __syncthreads();

        float a1 = 0.f, a2 = 0.f;
        #pragma unroll
        for (int c = 0; c < 64; ++c) {
            float fv = sfb[w][c];
            a1 = fmaf(fv, sf1[c * 64 + lane], a1);
            a2 = fmaf(fv, sf2[c * 64 + lane], a2);
        }
        if (p < TOTALP) {
            g1[(size_t)p * 64 + lane] = a1;
            g2[(size_t)p * 64 + lane] = a2;
            if (lane == 0) {
                float cx = xp[0], cy = xp[1], cz = xp[2];
                float n2 = __fadd_rn(__fadd_rn(__fmul_rn(cx, cx),
                                               __fmul_rn(cy, cy)),
                                     __fmul_rn(cz, cz));
                cand[p] = make_float4(cx, cy, cz, n2);
            }
        }
        __syncthreads();
    }
}

// ---------------- Kernel B: KNN scan, batched-bitonic selection ------------
// Metric (LOCKED, reference-replicating):
//   dot = fma(z,bz, fma(y,by, rn(x*bx)))
//   d   = rn_sub(rn_add(n2q, n2m), rn_mul(2, dot)), clamped >= 0
// Key = (u64)d_bits << 13 | idx  (tie -> smallest index, = lax.top_k).
// Selection: per-lane sorted sk[32] in regs; takes buffered 16-deep in LDS
// (slot-major [c][lane]); on __any(c==16): per-lane bitonic sort-16, then
// split of (sk[32] asc ++ rev(p[16] pad-inf)) -> upper-half min, then
// bitonic clean. Inter-wave merge: equal-length split + clean via LDS tree.
__global__ __launch_bounds__(512) void knn_scan_kernel(
    const float4* __restrict__ cand, int* __restrict__ idxo)
{
    // 64KB union: pend[SPLIT][PDEPTH][64] u64  |  mbuf[4][32][64] u64
    __shared__ u64 smem[8192];
    const int b = blockIdx.y;
    const int lane = threadIdx.x & 63;
    const int w = threadIdx.x >> 6;
    const int q = blockIdx.x * QPB + lane;   // 125*64 == 8000 exactly
    const float4* cb = cand + (size_t)b * NPTS;

    const float4 qv = cb[q];
    const float qx = qv.x, qy = qv.y, qz = qv.z, qn2 = qv.w;

    u64 sk[KSEL];
    #pragma unroll
    for (int i = 0; i < KSEL; ++i) sk[i] = ~0ULL;
    u64 thr = ~0ULL;
    int c = 0;
    u64* pend = smem + w * (PDEPTH * 64);

// per-lane: sort the <=c pendings (pad ALL j>=c to inf — avoids both junk
// and stale already-merged keys), bitonic split+clean into sorted sk[32].
// Split math: C = sk(asc,32) ++ rev(p'(asc,32; p'[16..31]=inf)) is bitonic;
// lo[i]=min(C[i],C[32+i])=min(sk[i], p'[31-i]); inf for i<16 -> only the
// UPPER half i=16..31 changes: sk[16+j]=min(sk[16+j], p[15-j]). Then clean.
#define DRAINB()                                                          \
    do {                                                                  \
        u64 p[PDEPTH];                                                    \
        _Pragma("unroll")                                                 \
        for (int j = 0; j < PDEPTH; ++j) p[j] = pend[j * 64 + lane];      \
        _Pragma("unroll")                                                 \
        for (int j = 0; j < PDEPTH; ++j) p[j] = (j < c) ? p[j] : ~0ULL;   \
        _Pragma("unroll")                                                 \
        for (int k = 2; k <= PDEPTH; k <<= 1) {                           \
            _Pragma("unroll")                                             \
            for (int j = k >> 1; j > 0; j >>= 1) {                        \
                _Pragma("unroll")                                         \
                for (int i = 0; i < PDEPTH; ++i) {                        \
                    if ((i & j) == 0) {                                   \
                        const int ip = i | j;                             \
                        const bool asc = ((i & k) == 0);                  \
                        u64 a = p[i], bb = p[ip];                         \
                        u64 lo = a < bb ? a : bb;                         \
                        u64 hi = a < bb ? bb : a;                         \
                        p[i]  = asc ? lo : hi;                            \
                        p[ip] = asc ? hi : lo;                            \
                    }                                                     \
                }                                                         \
            }                                                             \
        }                                                                 \
        _Pragma("unroll")                                                 \
        for (int j = 0; j < PDEPTH; ++j) {                                \
            u64 a = sk[16 + j], bb = p[PDEPTH - 1 - j];                   \
            sk[16 + j] = a < bb ? a : bb;                                 \
        }                                                                 \
        _Pragma("unroll")                                                 \
        for (int dd = 16; dd > 0; dd >>= 1) {                             \
            _Pragma("unroll")                                             \
            for (int i = 0; i < KSEL; ++i) {                              \
                if ((i & dd) == 0) {                                      \
                    const int ip = i | dd;                                \
                    u64 a = sk[i], bb = sk[ip];                           \
                    sk[i]  = a < bb ? a : bb;                             \
                    sk[ip] = a < bb ? bb : a;                             \
                }                                                         \
            }                                                             \
        }                                                                 \
        c = 0;                                                            \
        thr = sk[KSEL - 1];                                               \
    } while (0)

    const int c0 = w * CPW;
    #pragma unroll 1
    for (int i = 0; i < CPW; ++i) {
        const int ci = c0 + i;
        float4 cv = cb[ci];
        float dot = fmaf(qz, cv.z, fmaf(qy, cv.y, __fmul_rn(qx, cv.x)));
        float d = __fsub_rn(__fadd_rn(qn2, cv.w), __fmul_rn(2.0f, dot));
        d = fmaxf(d, 0.0f);  // only self can round negative; set-invariant
        u64 key = (((u64)__float_as_uint(d)) << 13) | (u64)ci;
        bool take = key < thr;
        pend[(size_t)c * 64 + lane] = key;  // always-write; j>=c masked at drain
        c += (int)take;
        if (__any(c == PDEPTH)) DRAINB();
    }
    DRAINB();
#undef DRAINB

// merge other sorted-32 (from LDS, slot-major) into sk: equal-length split
// lo[i]=min(sk[i], o[31-i]) for ALL i, then bitonic clean.
#define MERGE32(kidx)                                                     \
    do {                                                                  \
        u64 o[KSEL];                                                      \
        _Pragma("unroll")                                                 \
        for (int t = 0; t < KSEL; ++t)                                    \
            o[t] = smem[(kidx) * 2048 + t * 64 + lane];                   \
        _Pragma("unroll")                                                 \
        for (int i = 0; i < KSEL; ++i) {                                  \
            u64 a = sk[i], bb = o[KSEL - 1 - i];                          \
            sk[i] = a < bb ? a : bb;                                      \
        }                                                                 \
        _Pragma("unroll")                                                 \
        for (int dd = 16; dd > 0; dd >>= 1) {                             \
            _Pragma("unroll")                                             \
            for (int i = 0; i < KSEL; ++i) {                              \
                if ((i & dd) == 0) {                                      \
                    const int ip = i | dd;                                \
                    u64 a = sk[i], bb = sk[ip];                           \
                    sk[i]  = a < bb ? a : bb;                             \
                    sk[ip] = a < bb ? bb : a;                             \
                }                                                         \
            }                                                             \
        }                                                                 \
    } while (0)

    // merge tree: 8 sorted lists -> 1 (pend LDS dead; reuse as mbuf)
    __syncthreads();
    if (w & 1) {
        #pragma unroll
        for (int t = 0; t < KSEL; ++t)
            smem[(w >> 1) * 2048 + t * 64 + lane] = sk[t];
    }
    __syncthreads();
    if (!(w & 1)) MERGE32(w >> 1);
    __syncthreads();
    if ((w & 3) == 2) {
        #pragma unroll
        for (int t = 0; t < KSEL; ++t)
            smem[(w >> 2) * 2048 + t * 64 + lane] = sk[t];
    }
    __syncthreads();
    if ((w & 3) == 0 && (w & 4) == 0) MERGE32(0);
    if ((w & 3) == 0 && (w & 4) == 4) MERGE32(1);
    __syncthreads();
    if (w == 4) {
        #pragma unroll
        for (int t = 0; t < KSEL; ++t)
            smem[t * 64 + lane] = sk[t];
    }
    __syncthreads();
    if (w == 0) {
        MERGE32(0);
        int* op = idxo + ((size_t)b * NPTS + q) * KSEL;
        #pragma unroll
        for (int i = 0; i < KSEL; ++i) op[i] = (int)(sk[i] & 0x1FFFULL);
    }
#undef MERGE32
}

// ---------------- Kernel C: gather + edge + relu + maxpool (both fuses) ----
__global__ __launch_bounds__(256) void fuse_kernel(
    const float* __restrict__ g1, const float* __restrict__ g2,
    const int* __restrict__ idxo,
    const float* __restrict__ f1b, const float* __restrict__ f2b,
    float* __restrict__ fused)
{
    const int lane = threadIdx.x & 63;
    const int gw = (int)((blockIdx.x * 256 + threadIdx.x) >> 6);
    const int nw = 512 * 4;  // grid fixed at 512 blocks
    const float bias1 = f1b[lane];
    const float bias2 = f2b[lane];
    for (int p = gw; p < TOTALP; p += nw) {
        int b = p / NPTS;
        const int* mi = idxo + (size_t)p * KSEL;
        const float* G1 = g1 + (size_t)b * NPTS * 64;
        const float* G2 = g2 + (size_t)b * NPTS * 64;
        float base1 = bias1 - g1[(size_t)p * 64 + lane];
        float base2 = bias2 - g2[(size_t)p * 64 + lane];
        float a1 = 0.f, a2 = 0.f;
        #pragma unroll
        for (int k = 0; k < KSEL; ++k) {
            int j = mi[k];
            a1 = fmaxf(a1, G1[(size_t)j * 64 + lane] + base1);
            a2 = fmaxf(a2, G2[(size_t)j * 64 + lane] + base2);
        }
        fused[(size_t)p * 64 + lane] = a1 + a2;
    }
}

// ---------------- Kernel D: classifier MLP ----------------
__global__ __launch_bounds__(256) void cls_kernel(
    const float* __restrict__ fused,
    const float* __restrict__ cw1, const float* __restrict__ cb1,
    const float* __restrict__ cw2, const float* __restrict__ cb2,
    float* __restrict__ out)
{
    __shared__ float sw1[64 * 32];
    __shared__ float sw2[32 * 13];
    __shared__ float sb1[32];
    __shared__ float sb2[13];
    const int tid = threadIdx.x;
    for (int i = tid; i < 64 * 32; i += 256) sw1[i] = cw1[i];
    for (int i = tid; i < 32 * 13; i += 256) sw2[i] = cw2[i];
    if (tid < 32) sb1[tid] = cb1[tid];
    if (tid < 13) sb2[tid] = cb2[tid];
    __syncthreads();

    int p = blockIdx.x * 256 + tid;
    if (p >= TOTALP) return;

    float fu[64];
    const float4* fp = (const float4*)(fused + (size_t)p * 64);
    #pragma unroll
    for (int i = 0; i < 16; ++i) {
        float4 v = fp[i];
        fu[i * 4 + 0] = v.x; fu[i * 4 + 1] = v.y;
        fu[i * 4 + 2] = v.z; fu[i * 4 + 3] = v.w;
    }
    float h[32];
    #pragma unroll
    for (int j = 0; j < 32; j += 4) {
        float ax = sb1[j], ay = sb1[j + 1], az = sb1[j + 2], aw = sb1[j + 3];
        #pragma unroll
        for (int c = 0; c < 64; ++c) {
            float4 wv = *(const float4*)&sw1[c * 32 + j];
            ax = fmaf(fu[c], wv.x, ax);
            ay = fmaf(fu[c], wv.y, ay);
            az = fmaf(fu[c], wv.z, az);
            aw = fmaf(fu[c], wv.w, aw);
        }
        h[j] = fmaxf(ax, 0.f); h[j + 1] = fmaxf(ay, 0.f);
        h[j + 2] = fmaxf(az, 0.f); h[j + 3] = fmaxf(aw, 0.f);
    }
    float* op = out + (size_t)p * 13;
    #pragma unroll
    for (int o = 0; o < 13; ++o) {
        float acc = sb2[o];
        #pragma unroll
        for (int j = 0; j < 32; ++j) acc = fmaf(h[j], sw2[j * 13 + o], acc);
        op[o] = acc;
    }
}

extern "C" void kernel_launch(void* const* d_in, const int* in_sizes, int n_in,
                              void* d_out, int out_size, void* d_ws, size_t ws_size,
                              hipStream_t stream)
{
    const float* x   = (const float*)d_in[0];
    const float* ew1 = (const float*)d_in[1];
    const float* eb1 = (const float*)d_in[2];
    const float* ew2 = (const float*)d_in[3];
    const float* eb2 = (const float*)d_in[4];
    const float* f1w = (const float*)d_in[5];
    const float* f1b = (const float*)d_in[6];
    const float* f2w = (const float*)d_in[7];
    const float* f2b = (const float*)d_in[8];
    const float* cw1 = (const float*)d_in[9];
    const float* cb1 = (const float*)d_in[10];
    const float* cw2 = (const float*)d_in[11];
    const float* cb2 = (const float*)d_in[12];
    float* out = (float*)d_out;

    // workspace (~29.2 MB): [g1 8.2M][g2 8.2M][cand 0.5M][idxo 4.1M][fused 8.2M]
    float*  g1    = (float*)d_ws;
    float*  g2    = g1 + (size_t)TOTALP * 64;
    float4* cand  = (float4*)(g2 + (size_t)TOTALP * 64);
    int*    idxo  = (int*)(cand + (size_t)TOTALP);
    float*  fused = (float*)(idxo + (size_t)TOTALP * KSEL);

    hipLaunchKernelGGL(encode_kernel, dim3(256), dim3(256), 0, stream,
                       x, ew1, eb1, ew2, eb2, f1w, f2w, g1, g2, cand);
    hipLaunchKernelGGL(knn_scan_kernel, dim3(125, NBATCH), dim3(512), 0, stream,
                       cand, idxo);
    hipLaunchKernelGGL(fuse_kernel, dim3(512), dim3(256), 0, stream,
                       g1, g2, idxo, f1b, f2b, fused);
    hipLaunchKernelGGL(cls_kernel, dim3(125), dim3(256), 0, stream,
                       fused, cw1, cb1, cw2, cb2, out);
}

// Round 8
// 524.057 us; speedup vs baseline: 2.8205x; 1.3701x over previous
//
#include <hip/hip_runtime.h>
#include <stdint.h>

#define NPTS 8000
#define NBATCH 4
#define TOTALP (NBATCH * NPTS)
#define KSEL 32
#define QPB 64     /* queries per block (= lane) */
#define SPLIT 4    /* waves per block; wave w scans candidate range w */
#define CPW (NPTS / SPLIT)   /* 2000 */
#define PDEPTH 16  /* pending batch depth per lane */

typedef uint32_t u32;
typedef unsigned long long u64;

// ---------------- Kernel A: encoder + g1/g2 + cand(xyz,n2) precompute -----
__global__ __launch_bounds__(256) void encode_kernel(
    const float* __restrict__ x,
    const float* __restrict__ ew1, const float* __restrict__ eb1,
    const float* __restrict__ ew2, const float* __restrict__ eb2,
    const float* __restrict__ f1w, const float* __restrict__ f2w,
    float* __restrict__ g1, float* __restrict__ g2,
    float4* __restrict__ cand)
{
    __shared__ float sw1[9 * 64];
    __shared__ float sw2[64 * 64];
    __shared__ float sf1[64 * 64];
    __shared__ float sf2[64 * 64];
    __shared__ float sb1[64];
    __shared__ float sb2[64];
    __shared__ float shb[4][64];
    __shared__ float sfb[4][64];

    const int tid = threadIdx.x;
    for (int i = tid; i < 9 * 64; i += 256) sw1[i] = ew1[i];
    for (int i = tid; i < 64 * 64; i += 256) {
        sw2[i] = ew2[i]; sf1[i] = f1w[i]; sf2[i] = f2w[i];
    }
    if (tid < 64) { sb1[tid] = eb1[tid]; sb2[tid] = eb2[tid]; }
    __syncthreads();

    const int lane = tid & 63;
    const int w = tid >> 6;
    const int gw = blockIdx.x * 4 + w;
    const int nw = 256 * 4;  // grid fixed at 256 blocks

    #pragma unroll 1
    for (int it = 0; it < 32; ++it) {
        int p = gw + it * nw;
        int pc = p < TOTALP ? p : TOTALP - 1;
        const float* xp = x + (size_t)pc * 9;

        float acc = sb1[lane];
        #pragma unroll
        for (int i = 0; i < 9; ++i) acc = fmaf(xp[i], sw1[i * 64 + lane], acc);
        shb[w][lane] = fmaxf(acc, 0.f);
        __syncthreads();

        float fa = sb2[lane];
        #pragma unroll
        for (int c = 0; c < 64; ++c) fa = fmaf(shb[w][c], sw2[c * 64 + lane], fa);
        sfb[w][lane] = fa;
        __syncthreads();

        float a1 = 0.f, a2 = 0.f;
        #pragma unroll
        for (int c = 0; c < 64; ++c) {
            float fv = sfb[w][c];
            a1 = fmaf(fv, sf1[c * 64 + lane], a1);
            a2 = fmaf(fv, sf2[c * 64 + lane], a2);
        }
        if (p < TOTALP) {
            g1[(size_t)p * 64 + lane] = a1;
            g2[(size_t)p * 64 + lane] = a2;
            if (lane == 0) {
                float cx = xp[0], cy = xp[1], cz = xp[2];
                float n2 = __fadd_rn(__fadd_rn(__fmul_rn(cx, cx),
                                               __fmul_rn(cy, cy)),
                                     __fmul_rn(cz, cz));
                cand[p] = make_float4(cx, cy, cz, n2);
            }
        }
        __syncthreads();
    }
}

// ---------------- Kernel B: KNN scan, batched-bitonic selection ------------
// Metric (LOCKED, reference-replicating):
//   dot = fma(z,bz, fma(y,by, rn(x*bx)))
//   d   = rn_sub(rn_add(n2q, n2m), rn_mul(2, dot)), clamped >= 0
// Key = (u64)d_bits << 13 | idx  (tie -> smallest index, = lax.top_k).
// 256-thread blocks, 4 waves; lane = query, wave w scans 2000 candidates.
// Candidate loop manually unrolled x4 (4 independent wave-uniform loads to
// hide L1 latency); takes buffered 16-deep in LDS (slot-major [c][lane]);
// drain check once per group: __any(c >= 13) guarantees capacity (<=12+4).
__global__ __launch_bounds__(256) void knn_scan_kernel(
    const float4* __restrict__ cand, int* __restrict__ idxo)
{
    // 32KB: pend[SPLIT][PDEPTH][64] u64; merge phase reuses as 2x2048-u64 bufs
    __shared__ u64 smem[4096];
    const int b = blockIdx.y;
    const int lane = threadIdx.x & 63;
    const int w = threadIdx.x >> 6;
    const int q = blockIdx.x * QPB + lane;   // 125*64 == 8000 exactly
    const float4* cb = cand + (size_t)b * NPTS;

    const float4 qv = cb[q];
    const float qx = qv.x, qy = qv.y, qz = qv.z, qn2 = qv.w;

    u64 sk[KSEL];
    #pragma unroll
    for (int i = 0; i < KSEL; ++i) sk[i] = ~0ULL;
    u64 thr = ~0ULL;
    int c = 0;
    u64* pend = smem + w * (PDEPTH * 64);

// per-lane: sort the <=c pendings (pad ALL j>=c to inf), bitonic split+clean
// into sorted sk[32]. Split: only upper half changes (lower args are inf):
// sk[16+j] = min(sk[16+j], p[15-j]); then bitonic clean of sk[32].
#define DRAINB()                                                          \
    do {                                                                  \
        u64 p[PDEPTH];                                                    \
        _Pragma("unroll")                                                 \
        for (int j = 0; j < PDEPTH; ++j) p[j] = pend[j * 64 + lane];      \
        _Pragma("unroll")                                                 \
        for (int j = 0; j < PDEPTH; ++j) p[j] = (j < c) ? p[j] : ~0ULL;   \
        _Pragma("unroll")                                                 \
        for (int k = 2; k <= PDEPTH; k <<= 1) {                           \
            _Pragma("unroll")                                             \
            for (int j = k >> 1; j > 0; j >>= 1) {                        \
                _Pragma("unroll")                                         \
                for (int i = 0; i < PDEPTH; ++i) {                        \
                    if ((i & j) == 0) {                                   \
                        const int ip = i | j;                             \
                        const bool asc = ((i & k) == 0);                  \
                        u64 a = p[i], bb = p[ip];                         \
                        u64 lo = a < bb ? a : bb;                         \
                        u64 hi = a < bb ? bb : a;                         \
                        p[i]  = asc ? lo : hi;                            \
                        p[ip] = asc ? hi : lo;                            \
                    }                                                     \
                }                                                         \
            }                                                             \
        }                                                                 \
        _Pragma("unroll")                                                 \
        for (int j = 0; j < PDEPTH; ++j) {                                \
            u64 a = sk[16 + j], bb = p[PDEPTH - 1 - j];                   \
            sk[16 + j] = a < bb ? a : bb;                                 \
        }                                                                 \
        _Pragma("unroll")                                                 \
        for (int dd = 16; dd > 0; dd >>= 1) {                             \
            _Pragma("unroll")                                             \
            for (int i = 0; i < KSEL; ++i) {                              \
                if ((i & dd) == 0) {                                      \
                    const int ip = i | dd;                                \
                    u64 a = sk[i], bb = sk[ip];                           \
                    sk[i]  = a < bb ? a : bb;                             \
                    sk[ip] = a < bb ? bb : a;                             \
                }                                                         \
            }                                                             \
        }                                                                 \
        c = 0;                                                            \
        thr = sk[KSEL - 1];                                               \
    } while (0)

#define PROC(cv, ci_)                                                     \
    do {                                                                  \
        float dot_ = fmaf(qz, (cv).z, fmaf(qy, (cv).y, __fmul_rn(qx, (cv).x))); \
        float d_ = __fsub_rn(__fadd_rn(qn2, (cv).w), __fmul_rn(2.0f, dot_)); \
        d_ = fmaxf(d_, 0.0f);  /* only self can round negative; set-safe */ \
        u64 key_ = (((u64)__float_as_uint(d_)) << 13) | (u64)(ci_);       \
        bool take_ = key_ < thr;                                          \
        pend[(size_t)c * 64 + lane] = key_;                               \
        c += (int)take_;                                                  \
    } while (0)

    const int c0 = w * CPW;
    #pragma unroll 1
    for (int i = 0; i < CPW; i += 4) {
        const int ci = c0 + i;
        float4 cv0 = cb[ci + 0];
        float4 cv1 = cb[ci + 1];
        float4 cv2 = cb[ci + 2];
        float4 cv3 = cb[ci + 3];
        PROC(cv0, ci + 0);
        PROC(cv1, ci + 1);
        PROC(cv2, ci + 2);
        PROC(cv3, ci + 3);
        // capacity: entering group all lanes c<=12, +4 takes -> <=16. Drain.
        if (__any(c >= PDEPTH - 3)) DRAINB();
    }
    DRAINB();
#undef PROC
#undef DRAINB

// merge other sorted-32 (from LDS buffer kidx, slot-major) into sk:
// equal-length split lo[i]=min(sk[i], o[31-i]) for ALL i, then clean.
#define MERGE32(kidx)                                                     \
    do {                                                                  \
        u64 o[KSEL];                                                      \
        _Pragma("unroll")                                                 \
        for (int t = 0; t < KSEL; ++t)                                    \
            o[t] = smem[(kidx) * 2048 + t * 64 + lane];                   \
        _Pragma("unroll")                                                 \
        for (int i = 0; i < KSEL; ++i) {                                  \
            u64 a = sk[i], bb = o[KSEL - 1 - i];                          \
            sk[i] = a < bb ? a : bb;                                      \
        }                                                                 \
        _Pragma("unroll")                                                 \
        for (int dd = 16; dd > 0; dd >>= 1) {                             \
            _Pragma("unroll")                                             \
            for (int i = 0; i < KSEL; ++i) {                              \
                if ((i & dd) == 0) {                                      \
                    const int ip = i | dd;                                \
                    u64 a = sk[i], bb = sk[ip];                           \
                    sk[i]  = a < bb ? a : bb;                             \
                    sk[ip] = a < bb ? bb : a;                             \
                }                                                         \
            }                                                             \
        }                                                                 \
    } while (0)

    // merge tree: 4 sorted lists -> 1, two 2048-u64 buffers (pend is dead)
    __syncthreads();
    if (w == 1) {
        #pragma unroll
        for (int t = 0; t < KSEL; ++t) smem[t * 64 + lane] = sk[t];
    }
    if (w == 3) {
        #pragma unroll
        for (int t = 0; t < KSEL; ++t) smem[2048 + t * 64 + lane] = sk[t];
    }
    __syncthreads();
    if (w == 0) MERGE32(0);
    if (w == 2) MERGE32(1);
    __syncthreads();
    if (w == 2) {
        #pragma unroll
        for (int t = 0; t < KSEL; ++t) smem[t * 64 + lane] = sk[t];
    }
    __syncthreads();
    if (w == 0) {
        MERGE32(0);
        int* op = idxo + ((size_t)b * NPTS + q) * KSEL;
        #pragma unroll
        for (int i = 0; i < KSEL; ++i) op[i] = (int)(sk[i] & 0x1FFFULL);
    }
#undef MERGE32
}

// ---------------- Kernel C: gather + edge + relu + maxpool (both fuses) ----
__global__ __launch_bounds__(256) void fuse_kernel(
    const float* __restrict__ g1, const float* __restrict__ g2,
    const int* __restrict__ idxo,
    const float* __restrict__ f1b, const float* __restrict__ f2b,
    float* __restrict__ fused)
{
    const int lane = threadIdx.x & 63;
    const int gw = (int)((blockIdx.x * 256 + threadIdx.x) >> 6);
    const int nw = 512 * 4;  // grid fixed at 512 blocks
    const float bias1 = f1b[lane];
    const float bias2 = f2b[lane];
    for (int p = gw; p < TOTALP; p += nw) {
        int b = p / NPTS;
        const int* mi = idxo + (size_t)p * KSEL;
        const float* G1 = g1 + (size_t)b * NPTS * 64;
        const float* G2 = g2 + (size_t)b * NPTS * 64;
        float base1 = bias1 - g1[(size_t)p * 64 + lane];
        float base2 = bias2 - g2[(size_t)p * 64 + lane];
        float a1 = 0.f, a2 = 0.f;
        #pragma unroll
        for (int k = 0; k < KSEL; ++k) {
            int j = mi[k];
            a1 = fmaxf(a1, G1[(size_t)j * 64 + lane] + base1);
            a2 = fmaxf(a2, G2[(size_t)j * 64 + lane] + base2);
        }
        fused[(size_t)p * 64 + lane] = a1 + a2;
    }
}

// ---------------- Kernel D: classifier MLP ----------------
__global__ __launch_bounds__(256) void cls_kernel(
    const float* __restrict__ fused,
    const float* __restrict__ cw1, const float* __restrict__ cb1,
    const float* __restrict__ cw2, const float* __restrict__ cb2,
    float* __restrict__ out)
{
    __shared__ float sw1[64 * 32];
    __shared__ float sw2[32 * 13];
    __shared__ float sb1[32];
    __shared__ float sb2[13];
    const int tid = threadIdx.x;
    for (int i = tid; i < 64 * 32; i += 256) sw1[i] = cw1[i];
    for (int i = tid; i < 32 * 13; i += 256) sw2[i] = cw2[i];
    if (tid < 32) sb1[tid] = cb1[tid];
    if (tid < 13) sb2[tid] = cb2[tid];
    __syncthreads();

    int p = blockIdx.x * 256 + tid;
    if (p >= TOTALP) return;

    float fu[64];
    const float4* fp = (const float4*)(fused + (size_t)p * 64);
    #pragma unroll
    for (int i = 0; i < 16; ++i) {
        float4 v = fp[i];
        fu[i * 4 + 0] = v.x; fu[i * 4 + 1] = v.y;
        fu[i * 4 + 2] = v.z; fu[i * 4 + 3] = v.w;
    }
    float h[32];
    #pragma unroll
    for (int j = 0; j < 32; j += 4) {
        float ax = sb1[j], ay = sb1[j + 1], az = sb1[j + 2], aw = sb1[j + 3];
        #pragma unroll
        for (int c = 0; c < 64; ++c) {
            float4 wv = *(const float4*)&sw1[c * 32 + j];
            ax = fmaf(fu[c], wv.x, ax);
            ay = fmaf(fu[c], wv.y, ay);
            az = fmaf(fu[c], wv.z, az);
            aw = fmaf(fu[c], wv.w, aw);
        }
        h[j] = fmaxf(ax, 0.f); h[j + 1] = fmaxf(ay, 0.f);
        h[j + 2] = fmaxf(az, 0.f); h[j + 3] = fmaxf(aw, 0.f);
    }
    float* op = out + (size_t)p * 13;
    #pragma unroll
    for (int o = 0; o < 13; ++o) {
        float acc = sb2[o];
        #pragma unroll
        for (int j = 0; j < 32; ++j) acc = fmaf(h[j], sw2[j * 13 + o], acc);
        op[o] = acc;
    }
}

extern "C" void kernel_launch(void* const* d_in, const int* in_sizes, int n_in,
                              void* d_out, int out_size, void* d_ws, size_t ws_size,
                              hipStream_t stream)
{
    const float* x   = (const float*)d_in[0];
    const float* ew1 = (const float*)d_in[1];
    const float* eb1 = (const float*)d_in[2];
    const float* ew2 = (const float*)d_in[3];
    const float* eb2 = (const float*)d_in[4];
    const float* f1w = (const float*)d_in[5];
    const float* f1b = (const float*)d_in[6];
    const float* f2w = (const float*)d_in[7];
    const float* f2b = (const float*)d_in[8];
    const float* cw1 = (const float*)d_in[9];
    const float* cb1 = (const float*)d_in[10];
    const float* cw2 = (const float*)d_in[11];
    const float* cb2 = (const float*)d_in[12];
    float* out = (float*)d_out;

    // workspace (~29.2 MB): [g1 8.2M][g2 8.2M][cand 0.5M][idxo 4.1M][fused 8.2M]
    float*  g1    = (float*)d_ws;
    float*  g2    = g1 + (size_t)TOTALP * 64;
    float4* cand  = (float4*)(g2 + (size_t)TOTALP * 64);
    int*    idxo  = (int*)(cand + (size_t)TOTALP);
    float*  fused = (float*)(idxo + (size_t)TOTALP * KSEL);

    hipLaunchKernelGGL(encode_kernel, dim3(256), dim3(256), 0, stream,
                       x, ew1, eb1, ew2, eb2, f1w, f2w, g1, g2, cand);
    hipLaunchKernelGGL(knn_scan_kernel, dim3(125, NBATCH), dim3(256), 0, stream,
                       cand, idxo);
    hipLaunchKernelGGL(fuse_kernel, dim3(512), dim3(256), 0, stream,
                       g1, g2, idxo, f1b, f2b, fused);
    hipLaunchKernelGGL(cls_kernel, dim3(125), dim3(256), 0, stream,
                       fused, cw1, cb1, cw2, cb2, out);
}

// Round 9
// 497.727 us; speedup vs baseline: 2.9697x; 1.0529x over previous
//
#include <hip/hip_runtime.h>
#include <stdint.h>

#define NPTS 8000
#define NBATCH 4
#define TOTALP (NBATCH * NPTS)
#define KSEL 32
#define QPB 64      /* queries per block (= lane) */
#define SPLIT 4     /* waves per block */
#define CSPLIT 2    /* candidate halves across blockIdx.y */
#define CPW (NPTS / (CSPLIT * SPLIT))   /* 1000 */
#define PDEPTH 16   /* pending batch depth per lane */

typedef uint32_t u32;
typedef unsigned long long u64;

// ---------------- Kernel A: encoder + g1/g2 + cand(xyz,n2) precompute -----
// Barrier-free: shb/sfb rows are per-wave private; cross-lane visibility via
// s_waitcnt lgkmcnt(0) + wave_barrier (wave-synchronous LDS idiom).
__global__ __launch_bounds__(256) void encode_kernel(
    const float* __restrict__ x,
    const float* __restrict__ ew1, const float* __restrict__ eb1,
    const float* __restrict__ ew2, const float* __restrict__ eb2,
    const float* __restrict__ f1w, const float* __restrict__ f2w,
    float* __restrict__ g1, float* __restrict__ g2,
    float4* __restrict__ cand)
{
    __shared__ float sw1[9 * 64];
    __shared__ float sw2[64 * 64];
    __shared__ float sf1[64 * 64];
    __shared__ float sf2[64 * 64];
    __shared__ float sb1[64];
    __shared__ float sb2[64];
    __shared__ float shb[4][64];
    __shared__ float sfb[4][64];

    const int tid = threadIdx.x;
    for (int i = tid; i < 9 * 64; i += 256) sw1[i] = ew1[i];
    for (int i = tid; i < 64 * 64; i += 256) {
        sw2[i] = ew2[i]; sf1[i] = f1w[i]; sf2[i] = f2w[i];
    }
    if (tid < 64) { sb1[tid] = eb1[tid]; sb2[tid] = eb2[tid]; }
    __syncthreads();

    const int lane = tid & 63;
    const int w = tid >> 6;
    const int wave_id = blockIdx.x * 4 + w;   // grid fixed at 500 blocks

#define WSYNC() do { \
        asm volatile("s_waitcnt lgkmcnt(0)" ::: "memory"); \
        __builtin_amdgcn_wave_barrier(); \
    } while (0)

    #pragma unroll 1
    for (int it = 0; it < 16; ++it) {
        const int p = wave_id * 16 + it;      // 500*4*16 == 32000 exactly
        const float* xp = x + (size_t)p * 9;

        float acc = sb1[lane];
        #pragma unroll
        for (int i = 0; i < 9; ++i) acc = fmaf(xp[i], sw1[i * 64 + lane], acc);
        shb[w][lane] = fmaxf(acc, 0.f);
        WSYNC();

        float fa = sb2[lane];
        #pragma unroll
        for (int c = 0; c < 64; ++c) fa = fmaf(shb[w][c], sw2[c * 64 + lane], fa);
        WSYNC();
        sfb[w][lane] = fa;
        WSYNC();

        float a1 = 0.f, a2 = 0.f;
        #pragma unroll
        for (int c = 0; c < 64; ++c) {
            float fv = sfb[w][c];
            a1 = fmaf(fv, sf1[c * 64 + lane], a1);
            a2 = fmaf(fv, sf2[c * 64 + lane], a2);
        }
        WSYNC();
        g1[(size_t)p * 64 + lane] = a1;
        g2[(size_t)p * 64 + lane] = a2;
        if (lane == 0) {
            float cx = xp[0], cy = xp[1], cz = xp[2];
            float n2 = __fadd_rn(__fadd_rn(__fmul_rn(cx, cx),
                                           __fmul_rn(cy, cy)),
                                 __fmul_rn(cz, cz));
            cand[p] = make_float4(cx, cy, cz, n2);
        }
    }
#undef WSYNC
}

// ---------------- Kernel B: KNN scan, batched-bitonic selection ------------
// Metric (LOCKED, reference-replicating):
//   dot = fma(z,bz, fma(y,by, rn(x*bx)))
//   d   = rn_sub(rn_add(n2q, n2m), rn_mul(2, dot)), clamped >= 0
// Key = (u64)d_bits << 13 | idx  (tie -> smallest index, = lax.top_k).
// Grid (125, CSPLIT, B): block covers candidate half cs via 4 waves x 1000.
// Block-merged sorted-32 written to pk[cs][slot][TOTALP] (coalesced).
__global__ __launch_bounds__(256) void knn_scan_kernel(
    const float4* __restrict__ cand, u64* __restrict__ pk)
{
    // 32KB: pend[SPLIT][PDEPTH][64] u64; merge phase reuses as 2x2048-u64 bufs
    __shared__ u64 smem[4096];
    const int b = blockIdx.z;
    const int cs = blockIdx.y;
    const int lane = threadIdx.x & 63;
    const int w = threadIdx.x >> 6;
    const int q = blockIdx.x * QPB + lane;   // 125*64 == 8000 exactly
    const float4* cb = cand + (size_t)b * NPTS;

    const float4 qv = cb[q];
    const float qx = qv.x, qy = qv.y, qz = qv.z, qn2 = qv.w;

    u64 sk[KSEL];
    #pragma unroll
    for (int i = 0; i < KSEL; ++i) sk[i] = ~0ULL;
    u64 thr = ~0ULL;
    int c = 0;
    u64* pend = smem + w * (PDEPTH * 64);

#define DRAINB()                                                          \
    do {                                                                  \
        u64 p[PDEPTH];                                                    \
        _Pragma("unroll")                                                 \
        for (int j = 0; j < PDEPTH; ++j) p[j] = pend[j * 64 + lane];      \
        _Pragma("unroll")                                                 \
        for (int j = 0; j < PDEPTH; ++j) p[j] = (j < c) ? p[j] : ~0ULL;   \
        _Pragma("unroll")                                                 \
        for (int k = 2; k <= PDEPTH; k <<= 1) {                           \
            _Pragma("unroll")                                             \
            for (int j = k >> 1; j > 0; j >>= 1) {                        \
                _Pragma("unroll")                                         \
                for (int i = 0; i < PDEPTH; ++i) {                        \
                    if ((i & j) == 0) {                                   \
                        const int ip = i | j;                             \
                        const bool asc = ((i & k) == 0);                  \
                        u64 a = p[i], bb = p[ip];                         \
                        u64 lo = a < bb ? a : bb;                         \
                        u64 hi = a < bb ? bb : a;                         \
                        p[i]  = asc ? lo : hi;                            \
                        p[ip] = asc ? hi : lo;                            \
                    }                                                     \
                }                                                         \
            }                                                             \
        }                                                                 \
        _Pragma("unroll")                                                 \
        for (int j = 0; j < PDEPTH; ++j) {                                \
            u64 a = sk[16 + j], bb = p[PDEPTH - 1 - j];                   \
            sk[16 + j] = a < bb ? a : bb;                                 \
        }                                                                 \
        _Pragma("unroll")                                                 \
        for (int dd = 16; dd > 0; dd >>= 1) {                             \
            _Pragma("unroll")                                             \
            for (int i = 0; i < KSEL; ++i) {                              \
                if ((i & dd) == 0) {                                      \
                    const int ip = i | dd;                                \
                    u64 a = sk[i], bb = sk[ip];                           \
                    sk[i]  = a < bb ? a : bb;                             \
                    sk[ip] = a < bb ? bb : a;                             \
                }                                                         \
            }                                                             \
        }                                                                 \
        c = 0;                                                            \
        thr = sk[KSEL - 1];                                               \
    } while (0)

#define PROC(cv, ci_)                                                     \
    do {                                                                  \
        float dot_ = fmaf(qz, (cv).z, fmaf(qy, (cv).y, __fmul_rn(qx, (cv).x))); \
        float d_ = __fsub_rn(__fadd_rn(qn2, (cv).w), __fmul_rn(2.0f, dot_)); \
        d_ = fmaxf(d_, 0.0f);  /* only self can round negative; set-safe */ \
        u64 key_ = (((u64)__float_as_uint(d_)) << 13) | (u64)(ci_);       \
        bool take_ = key_ < thr;                                          \
        pend[(size_t)c * 64 + lane] = key_;                               \
        c += (int)take_;                                                  \
    } while (0)

    const int c0 = cs * (NPTS / CSPLIT) + w * CPW;
    #pragma unroll 1
    for (int i = 0; i < CPW; i += 4) {
        const int ci = c0 + i;
        float4 cv0 = cb[ci + 0];
        float4 cv1 = cb[ci + 1];
        float4 cv2 = cb[ci + 2];
        float4 cv3 = cb[ci + 3];
        PROC(cv0, ci + 0);
        PROC(cv1, ci + 1);
        PROC(cv2, ci + 2);
        PROC(cv3, ci + 3);
        // capacity: entering group all lanes c<=12, +4 takes -> <=16. Drain.
        if (__any(c >= PDEPTH - 3)) DRAINB();
    }
    DRAINB();
#undef PROC
#undef DRAINB

#define MERGE32(kidx)                                                     \
    do {                                                                  \
        u64 o[KSEL];                                                      \
        _Pragma("unroll")                                                 \
        for (int t = 0; t < KSEL; ++t)                                    \
            o[t] = smem[(kidx) * 2048 + t * 64 + lane];                   \
        _Pragma("unroll")                                                 \
        for (int i = 0; i < KSEL; ++i) {                                  \
            u64 a = sk[i], bb = o[KSEL - 1 - i];                          \
            sk[i] = a < bb ? a : bb;                                      \
        }                                                                 \
        _Pragma("unroll")                                                 \
        for (int dd = 16; dd > 0; dd >>= 1) {                             \
            _Pragma("unroll")                                             \
            for (int i = 0; i < KSEL; ++i) {                              \
                if ((i & dd) == 0) {                                      \
                    const int ip = i | dd;                                \
                    u64 a = sk[i], bb = sk[ip];                           \
                    sk[i]  = a < bb ? a : bb;                             \
                    sk[ip] = a < bb ? bb : a;                             \
                }                                                         \
            }                                                             \
        }                                                                 \
    } while (0)

    // merge tree: 4 sorted lists -> 1, two 2048-u64 buffers (pend is dead)
    __syncthreads();
    if (w == 1) {
        #pragma unroll
        for (int t = 0; t < KSEL; ++t) smem[t * 64 + lane] = sk[t];
    }
    if (w == 3) {
        #pragma unroll
        for (int t = 0; t < KSEL; ++t) smem[2048 + t * 64 + lane] = sk[t];
    }
    __syncthreads();
    if (w == 0) MERGE32(0);
    if (w == 2) MERGE32(1);
    __syncthreads();
    if (w == 2) {
        #pragma unroll
        for (int t = 0; t < KSEL; ++t) smem[t * 64 + lane] = sk[t];
    }
    __syncthreads();
    if (w == 0) {
        MERGE32(0);
        const size_t bq = (size_t)b * NPTS + q;
        #pragma unroll
        for (int t = 0; t < KSEL; ++t)
            pk[((size_t)(cs * KSEL + t)) * TOTALP + bq] = sk[t];
    }
#undef MERGE32
}

// ---------------- Kernel B2: merge the two candidate-half lists -----------
// Same total order on both halves -> lower-32 of bitonic merge == global
// top-32. Coalesced slot-major loads/stores. idxo layout: [k][TOTALP].
__global__ __launch_bounds__(256) void knn_final_kernel(
    const u64* __restrict__ pk, int* __restrict__ idxo)
{
    const int p = blockIdx.x * 256 + threadIdx.x;   // 125*256 == 32000

    u64 sk[KSEL], o[KSEL];
    #pragma unroll
    for (int t = 0; t < KSEL; ++t) sk[t] = pk[(size_t)t * TOTALP + p];
    #pragma unroll
    for (int t = 0; t < KSEL; ++t) o[t] = pk[(size_t)(KSEL + t) * TOTALP + p];

    #pragma unroll
    for (int i = 0; i < KSEL; ++i) {
        u64 a = sk[i], bb = o[KSEL - 1 - i];
        sk[i] = a < bb ? a : bb;
    }
    #pragma unroll
    for (int dd = 16; dd > 0; dd >>= 1) {
        #pragma unroll
        for (int i = 0; i < KSEL; ++i) {
            if ((i & dd) == 0) {
                const int ip = i | dd;
                u64 a = sk[i], bb = sk[ip];
                sk[i]  = a < bb ? a : bb;
                sk[ip] = a < bb ? bb : a;
            }
        }
    }
    #pragma unroll
    for (int t = 0; t < KSEL; ++t)
        idxo[(size_t)t * TOTALP + p] = (int)(sk[t] & 0x1FFFULL);
}

// ---------------- Kernel C: gather + edge + relu + maxpool (both fuses) ----
// Batch-local blocks: grid (125, B) -> per-block L2 working set = one batch's
// g1+g2 (4 MB, fits an XCD L2). Wave handles 16 contiguous points.
__global__ __launch_bounds__(256) void fuse_kernel(
    const float* __restrict__ g1, const float* __restrict__ g2,
    const int* __restrict__ idxo,
    const float* __restrict__ f1b, const float* __restrict__ f2b,
    float* __restrict__ fused)
{
    const int lane = threadIdx.x & 63;
    const int w = threadIdx.x >> 6;
    const int b = blockIdx.y;
    const int wchunk = blockIdx.x * 4 + w;   // 0..499
    const float bias1 = f1b[lane];
    const float bias2 = f2b[lane];
    const float* G1 = g1 + (size_t)b * NPTS * 64;
    const float* G2 = g2 + (size_t)b * NPTS * 64;

    #pragma unroll 1
    for (int it = 0; it < 16; ++it) {
        const int pl = wchunk * 16 + it;          // 500*16 == 8000 exactly
        const size_t p = (size_t)b * NPTS + pl;
        float base1 = bias1 - G1[(size_t)pl * 64 + lane];
        float base2 = bias2 - G2[(size_t)pl * 64 + lane];
        float a1 = 0.f, a2 = 0.f;
        #pragma unroll
        for (int k = 0; k < KSEL; ++k) {
            int j = idxo[(size_t)k * TOTALP + p];
            a1 = fmaxf(a1, G1[(size_t)j * 64 + lane] + base1);
            a2 = fmaxf(a2, G2[(size_t)j * 64 + lane] + base2);
        }
        fused[p * 64 + lane] = a1 + a2;
    }
}

// ---------------- Kernel D: classifier MLP ----------------
__global__ __launch_bounds__(256) void cls_kernel(
    const float* __restrict__ fused,
    const float* __restrict__ cw1, const float* __restrict__ cb1,
    const float* __restrict__ cw2, const float* __restrict__ cb2,
    float* __restrict__ out)
{
    __shared__ float sw1[64 * 32];
    __shared__ float sw2[32 * 13];
    __shared__ float sb1[32];
    __shared__ float sb2[13];
    const int tid = threadIdx.x;
    for (int i = tid; i < 64 * 32; i += 256) sw1[i] = cw1[i];
    for (int i = tid; i < 32 * 13; i += 256) sw2[i] = cw2[i];
    if (tid < 32) sb1[tid] = cb1[tid];
    if (tid < 13) sb2[tid] = cb2[tid];
    __syncthreads();

    int p = blockIdx.x * 256 + tid;
    if (p >= TOTALP) return;

    float fu[64];
    const float4* fp = (const float4*)(fused + (size_t)p * 64);
    #pragma unroll
    for (int i = 0; i < 16; ++i) {
        float4 v = fp[i];
        fu[i * 4 + 0] = v.x; fu[i * 4 + 1] = v.y;
        fu[i * 4 + 2] = v.z; fu[i * 4 + 3] = v.w;
    }
    float h[32];
    #pragma unroll
    for (int j = 0; j < 32; j += 4) {
        float ax = sb1[j], ay = sb1[j + 1], az = sb1[j + 2], aw = sb1[j + 3];
        #pragma unroll
        for (int c = 0; c < 64; ++c) {
            float4 wv = *(const float4*)&sw1[c * 32 + j];
            ax = fmaf(fu[c], wv.x, ax);
            ay = fmaf(fu[c], wv.y, ay);
            az = fmaf(fu[c], wv.z, az);
            aw = fmaf(fu[c], wv.w, aw);
        }
        h[j] = fmaxf(ax, 0.f); h[j + 1] = fmaxf(ay, 0.f);
        h[j + 2] = fmaxf(az, 0.f); h[j + 3] = fmaxf(aw, 0.f);
    }
    float* op = out + (size_t)p * 13;
    #pragma unroll
    for (int o = 0; o < 13; ++o) {
        float acc = sb2[o];
        #pragma unroll
        for (int j = 0; j < 32; ++j) acc = fmaf(h[j], sw2[j * 13 + o], acc);
        op[o] = acc;
    }
}

extern "C" void kernel_launch(void* const* d_in, const int* in_sizes, int n_in,
                              void* d_out, int out_size, void* d_ws, size_t ws_size,
                              hipStream_t stream)
{
    const float* x   = (const float*)d_in[0];
    const float* ew1 = (const float*)d_in[1];
    const float* eb1 = (const float*)d_in[2];
    const float* ew2 = (const float*)d_in[3];
    const float* eb2 = (const float*)d_in[4];
    const float* f1w = (const float*)d_in[5];
    const float* f1b = (const float*)d_in[6];
    const float* f2w = (const float*)d_in[7];
    const float* f2b = (const float*)d_in[8];
    const float* cw1 = (const float*)d_in[9];
    const float* cb1 = (const float*)d_in[10];
    const float* cw2 = (const float*)d_in[11];
    const float* cb2 = (const float*)d_in[12];
    float* out = (float*)d_out;

    // workspace (~37.4 MB): [g1 8.2][g2 8.2][cand 0.5][idxo 4.1][pk 16.4]
    // 'fused' aliases pk (pk dead after knn_final_kernel).
    float*  g1    = (float*)d_ws;
    float*  g2    = g1 + (size_t)TOTALP * 64;
    float4* cand  = (float4*)(g2 + (size_t)TOTALP * 64);
    int*    idxo  = (int*)(cand + (size_t)TOTALP);
    u64*    pk    = (u64*)(idxo + (size_t)TOTALP * KSEL);
    float*  fused = (float*)pk;

    hipLaunchKernelGGL(encode_kernel, dim3(500), dim3(256), 0, stream,
                       x, ew1, eb1, ew2, eb2, f1w, f2w, g1, g2, cand);
    hipLaunchKernelGGL(knn_scan_kernel, dim3(125, CSPLIT, NBATCH), dim3(256), 0,
                       stream, cand, pk);
    hipLaunchKernelGGL(knn_final_kernel, dim3(125), dim3(256), 0, stream,
                       pk, idxo);
    hipLaunchKernelGGL(fuse_kernel, dim3(125, NBATCH), dim3(256), 0, stream,
                       g1, g2, idxo, f1b, f2b, fused);
    hipLaunchKernelGGL(cls_kernel, dim3(125), dim3(256), 0, stream,
                       fused, cw1, cb1, cw2, cb2, out);
}